// Round 1
// baseline (501.764 us; speedup 1.0000x reference)
//
#include <hip/hip_runtime.h>

#define NR 8192
#define FIN 2048
#define FOUT 256
#define ALPHA 0.2f

typedef float f32x4 __attribute__((ext_vector_type(4)));
typedef float f32x16 __attribute__((ext_vector_type(16)));
typedef int i32x4 __attribute__((ext_vector_type(4)));
typedef unsigned int u32x4 __attribute__((ext_vector_type(4)));
typedef unsigned short u16x4 __attribute__((ext_vector_type(4)));
typedef unsigned short u16x8 __attribute__((ext_vector_type(8)));
typedef __bf16 bf16x8 __attribute__((ext_vector_type(8)));

__device__ __forceinline__ unsigned short f2bf(float f){
  unsigned u = __float_as_uint(f);
  return (unsigned short)((u + 0x7fffu + ((u >> 16) & 1u)) >> 16);
}
__device__ __forceinline__ float bf2f(unsigned short b){
  return __uint_as_float(((unsigned)b) << 16);
}

// ---------------- K1: bucket rows by camera (deterministic, 1 block) ----------
__global__ void k_bucket(const int* __restrict__ cam, int* __restrict__ rowlist,
                         int* __restrict__ camBase, int* __restrict__ camCount){
  __shared__ int cnt[256][8];
  __shared__ int base[8];
  int t = threadIdx.x;
  int loc[8];
  #pragma unroll
  for (int c = 0; c < 8; c++) loc[c] = 0;
  for (int k = 0; k < 32; k++){ int n = t*32 + k; loc[cam[n] & 7]++; }
  #pragma unroll
  for (int c = 0; c < 8; c++) cnt[t][c] = loc[c];
  __syncthreads();
  if (t < 8){
    int s = 0;
    for (int i = 0; i < 256; i++){ int v = cnt[i][t]; cnt[i][t] = s; s += v; }
    camCount[t] = s;
    base[t] = s;
  }
  __syncthreads();
  if (t == 0){
    int s = 0;
    for (int c = 0; c < 8; c++){ int v = base[c]; base[c] = s; camBase[c] = s; s += v; }
  }
  __syncthreads();
  int off[8];
  #pragma unroll
  for (int c = 0; c < 8; c++) off[c] = base[c] + cnt[t][c];
  for (int k = 0; k < 32; k++){
    int n = t*32 + k; int c = cam[n] & 7;
    rowlist[off[c]++] = n;
  }
}

// ---------------- K2: gather GEMM  h = x[rows] @ W[c]  (fp32) -----------------
__global__ __launch_bounds__(256) void k_gemm(const float* __restrict__ x,
    const float* __restrict__ W, const int* __restrict__ rowlist,
    const int* __restrict__ camBase, const int* __restrict__ camCount,
    float* __restrict__ h, unsigned short* __restrict__ hbf){
  int c = blockIdx.y;
  int cnt = camCount[c];
  int tile = blockIdx.x;
  if (tile * 16 >= cnt) return;
  __shared__ float xl[16][36];
  __shared__ int rows[16];
  int t = threadIdx.x;
  if (t < 16){
    int idx = tile*16 + t;
    rows[t] = (idx < cnt) ? rowlist[camBase[c] + idx] : -1;
  }
  __syncthreads();
  int tc = t & 63, tr = t >> 6;
  float acc[4][4];
  #pragma unroll
  for (int i = 0; i < 4; i++)
    #pragma unroll
    for (int j = 0; j < 4; j++) acc[i][j] = 0.f;
  const float* Wc = W + (size_t)c*FIN*FOUT + tc*4;
  for (int d0 = 0; d0 < FIN; d0 += 32){
    #pragma unroll
    for (int e2 = 0; e2 < 2; e2++){
      int e = t + e2*256;
      int r = e >> 5, dd = e & 31;
      int row = rows[r];
      xl[r][dd] = (row >= 0) ? x[(size_t)row*FIN + d0 + dd] : 0.f;
    }
    __syncthreads();
    #pragma unroll
    for (int q = 0; q < 8; q++){
      f32x4 xr[4];
      #pragma unroll
      for (int rr = 0; rr < 4; rr++) xr[rr] = *(const f32x4*)&xl[tr*4 + rr][q*4];
      f32x4 wq[4];
      #pragma unroll
      for (int qq = 0; qq < 4; qq++)
        wq[qq] = *(const f32x4*)(Wc + (size_t)(d0 + q*4 + qq)*FOUT);
      #pragma unroll
      for (int qq = 0; qq < 4; qq++)
        #pragma unroll
        for (int rr = 0; rr < 4; rr++)
          #pragma unroll
          for (int cc2 = 0; cc2 < 4; cc2++)
            acc[rr][cc2] = fmaf(xr[rr][qq], wq[qq][cc2], acc[rr][cc2]);
    }
    __syncthreads();
  }
  #pragma unroll
  for (int rr = 0; rr < 4; rr++){
    int row = rows[tr*4 + rr];
    if (row < 0) continue;
    f32x4 v; u16x4 pk;
    #pragma unroll
    for (int cc2 = 0; cc2 < 4; cc2++){ v[cc2] = acc[rr][cc2]; pk[cc2] = f2bf(acc[rr][cc2]); }
    *(f32x4*)(h + (size_t)row*FOUT + tc*4) = v;
    *(u16x4*)(hbf + (size_t)row*FOUT + tc*4) = pk;
  }
}

// ---------------- K3: s1 = h@a1, s2 = h@a2, per-block max(s2) -----------------
__global__ void k_svec(const float* __restrict__ h, const float* __restrict__ a,
                       float* __restrict__ s1, float* __restrict__ s2,
                       float* __restrict__ bm){
  __shared__ float a1l[FOUT], a2l[FOUT];
  __shared__ float red[128];
  int t = threadIdx.x;
  for (int k = t; k < FOUT; k += 128){ a1l[k] = a[k]; a2l[k] = a[FOUT + k]; }
  __syncthreads();
  int n = blockIdx.x*128 + t;
  const f32x4* h4 = (const f32x4*)(h + (size_t)n*FOUT);
  float acc1 = 0.f, acc2 = 0.f;
  #pragma unroll 4
  for (int q = 0; q < 64; q++){
    f32x4 hv = h4[q];
    f32x4 a1v = *(const f32x4*)&a1l[q*4];
    f32x4 a2v = *(const f32x4*)&a2l[q*4];
    #pragma unroll
    for (int e = 0; e < 4; e++){
      acc1 = fmaf(hv[e], a1v[e], acc1);
      acc2 = fmaf(hv[e], a2v[e], acc2);
    }
  }
  s1[n] = acc1; s2[n] = acc2;
  red[t] = acc2;
  __syncthreads();
  for (int s = 64; s > 0; s >>= 1){
    if (t < s) red[t] = fmaxf(red[t], red[t + s]);
    __syncthreads();
  }
  if (t == 0) bm[blockIdx.x] = red[0];
}

// ---------------- K4: transpose h_bf16 [NR][FOUT] -> hT [FOUT][NR] ------------
__global__ void k_transpose(const unsigned short* __restrict__ in,
                            unsigned short* __restrict__ out){
  __shared__ unsigned short tl[64][72];
  int t = threadIdx.x;
  int j0 = blockIdx.x*64, c0 = blockIdx.y*64;
  {
    int jj = t >> 2, cq = (t & 3)*16;
    union { u32x4 v[2]; unsigned short s[16]; } buf;
    const u32x4* src = (const u32x4*)(in + (size_t)(j0 + jj)*FOUT + c0 + cq);
    buf.v[0] = src[0]; buf.v[1] = src[1];
    #pragma unroll
    for (int k = 0; k < 16; k++) tl[cq + k][jj] = buf.s[k];
  }
  __syncthreads();
  {
    int cc = t >> 2, jq = (t & 3)*16;
    union { u32x4 v[2]; unsigned short s[16]; } buf;
    #pragma unroll
    for (int k = 0; k < 16; k++) buf.s[k] = tl[cc][jq + k];
    u32x4* dst = (u32x4*)(out + (size_t)(c0 + cc)*NR + j0 + jq);
    dst[0] = buf.v[0]; dst[1] = buf.v[1];
  }
}

// ---------------- K5: fused masked-softmax attention x h (flash-like) ---------
__global__ __launch_bounds__(512) void k_flash(const int* __restrict__ adj,
    const float* __restrict__ s1g, const float* __restrict__ s2g,
    const float* __restrict__ bm, const unsigned short* __restrict__ hT,
    float* __restrict__ hp, float* __restrict__ Dp, int jchunks){
  __shared__ unsigned short pl[64][72];
  __shared__ float s1l[64], ml[64], Dl[64], red[64];
  int t = threadIdx.x;
  int i0 = blockIdx.x*64;
  int jc = blockIdx.y;
  int nj = NR / jchunks;
  int jbase = jc * nj;
  // global max of s2 (upper bound for the softmax shift)
  if (t < 64) red[t] = bm[t];
  __syncthreads();
  if (t < 8){ float v = red[t]; for (int k = t + 8; k < 64; k += 8) v = fmaxf(v, red[k]); red[t] = v; }
  __syncthreads();
  if (t == 0){ float v = red[0]; for (int k = 1; k < 8; k++) v = fmaxf(v, red[k]); red[0] = v; }
  __syncthreads();
  float maxS2 = red[0];
  if (t < 64){
    float sv = s1g[i0 + t];
    s1l[t] = sv;
    float mm = sv + maxS2;
    ml[t] = fmaxf(mm, ALPHA*mm);   // leaky_relu upper bound (monotone)
  }
  __syncthreads();
  int il = t >> 3, tj = t & 7;         // p-generation roles
  int w = t >> 6, lane = t & 63;       // MFMA roles
  float s1i = s1l[il], mi = ml[il];
  float Dacc = 0.f;
  f32x16 acc0, acc1;
  #pragma unroll
  for (int k = 0; k < 16; k++){ acc0[k] = 0.f; acc1[k] = 0.f; }
  const unsigned short* hTw = hT + (size_t)(w*32 + (lane & 31))*NR;
  const int* arow = adj + (size_t)(i0 + il)*NR + jbase + tj*8;
  for (int jt = 0; jt < nj; jt += 64){
    int j0 = jbase + jt;
    i32x4 ad0 = __builtin_nontemporal_load((const i32x4*)arow);
    i32x4 ad1 = __builtin_nontemporal_load(((const i32x4*)arow) + 1);
    arow += 64;
    f32x4 s20 = *(const f32x4*)(s2g + j0 + tj*8);
    f32x4 s21 = *(const f32x4*)(s2g + j0 + tj*8 + 4);
    u16x8 pu;
    float Dloc = 0.f;
    #pragma unroll
    for (int e = 0; e < 4; e++){
      float e0 = s1i + s20[e]; e0 = fmaxf(e0, ALPHA*e0);
      float p0 = (ad0[e] > 0) ? __expf(e0 - mi) : 0.f;
      unsigned short b0 = f2bf(p0); pu[e] = b0; Dloc += bf2f(b0);
      float e1 = s1i + s21[e]; e1 = fmaxf(e1, ALPHA*e1);
      float p1 = (ad1[e] > 0) ? __expf(e1 - mi) : 0.f;
      unsigned short b1 = f2bf(p1); pu[e + 4] = b1; Dloc += bf2f(b1);
    }
    Dacc += Dloc;
    // prefetch B fragments (independent of pl) before the barrier
    bf16x8 bfr[4];
    #pragma unroll
    for (int ks = 0; ks < 4; ks++){
      int koff = ks*16 + (lane >> 5)*8;
      bfr[ks] = *(const bf16x8*)(hTw + j0 + koff);
    }
    *(u16x8*)&pl[il][tj*8] = pu;
    __syncthreads();
    #pragma unroll
    for (int ks = 0; ks < 4; ks++){
      int koff = ks*16 + (lane >> 5)*8;
      bf16x8 a0 = *(const bf16x8*)&pl[lane & 31][koff];
      acc0 = __builtin_amdgcn_mfma_f32_32x32x16_bf16(a0, bfr[ks], acc0, 0, 0, 0);
      bf16x8 a1 = *(const bf16x8*)&pl[32 + (lane & 31)][koff];
      acc1 = __builtin_amdgcn_mfma_f32_32x32x16_bf16(a1, bfr[ks], acc1, 0, 0, 0);
    }
    __syncthreads();
  }
  // reduce D over the 8 tj lanes (lane bits 0..2)
  Dacc += __shfl_xor(Dacc, 1);
  Dacc += __shfl_xor(Dacc, 2);
  Dacc += __shfl_xor(Dacc, 4);
  if (tj == 0) Dl[il] = Dacc;
  __syncthreads();
  if (t < 64) Dp[(size_t)jc*NR + i0 + t] = Dl[t];
  float* hpb = hp + (size_t)jc*NR*FOUT;
  int col = w*32 + (lane & 31);
  #pragma unroll
  for (int r = 0; r < 16; r++){
    int rowl = (r & 3) + 8*(r >> 2) + 4*(lane >> 5);
    hpb[(size_t)(i0 + rowl)*FOUT + col] = acc0[r];
    hpb[(size_t)(i0 + 32 + rowl)*FOUT + col] = acc1[r];
  }
}

// ---------------- K6: combine partials, normalize, ELU ------------------------
__global__ void k_final(const float* __restrict__ hp, const float* __restrict__ Dp,
                        float* __restrict__ out, int jchunks){
  int g = blockIdx.x*256 + threadIdx.x;
  int i = g >> 6, cg = (g & 63)*4;
  f32x4 s; s[0] = s[1] = s[2] = s[3] = 0.f;
  float D = 0.f;
  for (int jc = 0; jc < jchunks; jc++){
    f32x4 v = *(const f32x4*)(hp + ((size_t)jc*NR + i)*FOUT + cg);
    s += v;
    D += Dp[(size_t)jc*NR + i];
  }
  float inv = (D > 0.f) ? 1.f / D : 0.f;
  f32x4 o;
  #pragma unroll
  for (int e = 0; e < 4; e++){
    float v = s[e]*inv;
    o[e] = (v > 0.f) ? v : expm1f(v);
  }
  *(f32x4*)(out + (size_t)i*FOUT + cg) = o;
}

extern "C" void kernel_launch(void* const* d_in, const int* in_sizes, int n_in,
                              void* d_out, int out_size, void* d_ws, size_t ws_size,
                              hipStream_t stream){
  (void)in_sizes; (void)n_in; (void)out_size;
  const float* x   = (const float*)d_in[0];
  const float* W   = (const float*)d_in[1];
  const float* a   = (const float*)d_in[2];
  const int*   cam = (const int*)d_in[3];
  const int*   adj = (const int*)d_in[4];
  float* out = (float*)d_out;
  char* ws = (char*)d_ws;
  size_t off = 0;
  auto alloc = [&](size_t b) -> void* {
    void* p = ws + off; off = (off + b + 255) & ~(size_t)255; return p;
  };
  int* rowlist  = (int*)alloc((size_t)NR*4);
  int* camBase  = (int*)alloc(64);
  int* camCount = (int*)alloc(64);
  float* h          = (float*)alloc((size_t)NR*FOUT*4);
  unsigned short* hbf = (unsigned short*)alloc((size_t)NR*FOUT*2);
  unsigned short* hT  = (unsigned short*)alloc((size_t)NR*FOUT*2);
  float* s1 = (float*)alloc((size_t)NR*4);
  float* s2 = (float*)alloc((size_t)NR*4);
  float* bm = (float*)alloc(64*4);
  size_t fixed = off;
  size_t per_chunk = (size_t)NR*4 + (size_t)NR*FOUT*4 + 1024;
  int JC = 4;
  while (JC > 1 && fixed + (size_t)JC*per_chunk > ws_size) JC >>= 1;
  bool fits = fixed + (size_t)JC*per_chunk <= ws_size;
  float* Dp = (float*)alloc((size_t)JC*NR*4);
  float* hp = fits ? (float*)alloc((size_t)JC*NR*FOUT*4) : out;

  hipLaunchKernelGGL(k_bucket, dim3(1), dim3(256), 0, stream,
                     cam, rowlist, camBase, camCount);
  hipLaunchKernelGGL(k_gemm, dim3(512, 8), dim3(256), 0, stream,
                     x, W, rowlist, camBase, camCount, h, hbf);
  hipLaunchKernelGGL(k_svec, dim3(64), dim3(128), 0, stream, h, a, s1, s2, bm);
  hipLaunchKernelGGL(k_transpose, dim3(NR/64, FOUT/64), dim3(256), 0, stream, hbf, hT);
  hipLaunchKernelGGL(k_flash, dim3(NR/64, JC), dim3(512), 0, stream,
                     adj, s1, s2, bm, hT, hp, Dp, JC);
  hipLaunchKernelGGL(k_final, dim3((NR*FOUT/4)/256), dim3(256), 0, stream,
                     hp, Dp, out, JC);
}

// Round 2
// 258.017 us; speedup vs baseline: 1.9447x; 1.9447x over previous
//
#include <hip/hip_runtime.h>

#define NR 8192
#define FIN 2048
#define FOUT 256
#define ALPHA 0.2f
#define NTMAX 136

typedef float f32x4 __attribute__((ext_vector_type(4)));
typedef float f32x16 __attribute__((ext_vector_type(16)));
typedef int i32x4 __attribute__((ext_vector_type(4)));
typedef unsigned int u32x4 __attribute__((ext_vector_type(4)));
typedef unsigned short u16x4 __attribute__((ext_vector_type(4)));
typedef unsigned short u16x8 __attribute__((ext_vector_type(8)));
typedef __bf16 bf16x8 __attribute__((ext_vector_type(8)));
typedef _Float16 f16x8 __attribute__((ext_vector_type(8)));
typedef _Float16 f16x4 __attribute__((ext_vector_type(4)));

__device__ __forceinline__ unsigned short f2bf(float f){
  unsigned u = __float_as_uint(f);
  return (unsigned short)((u + 0x7fffu + ((u >> 16) & 1u)) >> 16);
}
__device__ __forceinline__ float bf2f(unsigned short b){
  return __uint_as_float(((unsigned)b) << 16);
}

__device__ __forceinline__ void gload16(const void* gptr, void* lptr){
  __builtin_amdgcn_global_load_lds(
      (const __attribute__((address_space(1))) unsigned int*)gptr,
      (__attribute__((address_space(3))) unsigned int*)lptr, 16, 0, 0);
}

// ---------------- K1: bucket rows by camera + tile table (1 block) -----------
__global__ void k_bucket(const int* __restrict__ cam, int* __restrict__ rowlist,
                         int* __restrict__ tileCam, int* __restrict__ prows){
  __shared__ int cnt[256][8];
  __shared__ int base[8];
  __shared__ int scnt[8];
  __shared__ int tstart[9];
  __shared__ int tcL[NTMAX], tlocL[NTMAX];
  int t = threadIdx.x;
  int loc[8];
  #pragma unroll
  for (int c = 0; c < 8; c++) loc[c] = 0;
  for (int k = 0; k < 32; k++){ int n = t*32 + k; loc[cam[n] & 7]++; }
  #pragma unroll
  for (int c = 0; c < 8; c++) cnt[t][c] = loc[c];
  __syncthreads();
  if (t < 8){
    int s = 0;
    for (int i = 0; i < 256; i++){ int v = cnt[i][t]; cnt[i][t] = s; s += v; }
    scnt[t] = s;
  }
  __syncthreads();
  if (t == 0){
    int s = 0;
    for (int c = 0; c < 8; c++){ base[c] = s; s += scnt[c]; }
    int ts = 0;
    for (int c = 0; c < 8; c++){ tstart[c] = ts; ts += (scnt[c] + 63) >> 6; }
    tstart[8] = ts;
  }
  __syncthreads();
  int off[8];
  #pragma unroll
  for (int c = 0; c < 8; c++) off[c] = base[c] + cnt[t][c];
  for (int k = 0; k < 32; k++){
    int n = t*32 + k; int c = cam[n] & 7;
    rowlist[off[c]++] = n;
  }
  __syncthreads();
  if (t < NTMAX){
    int tc = -1, tl = 0;
    if (t < tstart[8]){
      for (int c = 0; c < 8; c++)
        if (t >= tstart[c] && t < tstart[c+1]){ tc = c; tl = t - tstart[c]; }
    }
    tcL[t] = tc; tlocL[t] = tl;
    tileCam[t] = tc;
  }
  __syncthreads();
  for (int s = t; s < NTMAX*64; s += 256){
    int tile = s >> 6;
    int c = tcL[tile];
    int v = -1;
    if (c >= 0){
      int li = tlocL[tile]*64 + (s & 63);
      if (li < scnt[c]) v = rowlist[base[c] + li];
    }
    prows[s] = v;
  }
}

// ---------------- K2a: x fp32 -> fp16 ----------------------------------------
__global__ __launch_bounds__(256) void k_xhalf(const float* __restrict__ x,
                                               _Float16* __restrict__ xh){
  size_t b0 = ((size_t)blockIdx.x*256 + threadIdx.x)*32;
  #pragma unroll
  for (int q = 0; q < 8; q++){
    f32x4 v = *(const f32x4*)(x + b0 + q*4);
    f16x4 h;
    #pragma unroll
    for (int e = 0; e < 4; e++) h[e] = (_Float16)v[e];
    *(f16x4*)(xh + b0 + q*4) = h;
  }
}

// ---------------- K2b: W[c][k][n] fp32 -> WhT[c][n][k] fp16 -------------------
__global__ __launch_bounds__(256) void k_wth(const float* __restrict__ W,
                                             _Float16* __restrict__ WhT){
  __shared__ _Float16 tl[64][72];
  int t = threadIdx.x;
  int k0 = blockIdx.x*64, n0 = blockIdx.y*64, c = blockIdx.z;
  {
    int kk = t >> 2, nq = (t & 3)*16;
    const float* src = W + ((size_t)c*FIN + k0 + kk)*FOUT + n0 + nq;
    #pragma unroll
    for (int q = 0; q < 4; q++){
      f32x4 v = *(const f32x4*)(src + q*4);
      #pragma unroll
      for (int e = 0; e < 4; e++) tl[nq + q*4 + e][kk] = (_Float16)v[e];
    }
  }
  __syncthreads();
  {
    int nn = t >> 2, kq = (t & 3)*16;
    union { u32x4 v[2]; _Float16 s[16]; } buf;
    #pragma unroll
    for (int e = 0; e < 16; e++) buf.s[e] = tl[nn][kq + e];
    u32x4* dst = (u32x4*)(WhT + ((size_t)c*FOUT + n0 + nn)*FIN + k0 + kq);
    dst[0] = buf.v[0]; dst[1] = buf.v[1];
  }
}

// ---------------- K3: MFMA gather GEMM  partial[ks] = x[rows] @ W[c] ----------
// Block: 64 rows x 256 cols, 4 waves (2x2), BK=32 double-buffered, split-K.
// A,B staged in fragment layout via per-lane-gather global_load_lds.
__global__ __launch_bounds__(256) void k_gmm(const _Float16* __restrict__ xh,
    const _Float16* __restrict__ WhT, const int* __restrict__ tileCam,
    const int* __restrict__ prows, float* __restrict__ partial, int klen){
  __shared__ _Float16 ab[2][10240];   // [A:2048 | B:8192] halfs per buffer
  __shared__ int rows[64];
  __shared__ int growL[64];
  int tile = blockIdx.x;
  int cam = tileCam[tile];
  if (cam < 0) return;
  int t = threadIdx.x;
  if (t < 64){ int r = prows[tile*64 + t]; rows[t] = r; growL[t] = (r < 0) ? 0 : r; }
  __syncthreads();
  int ks = blockIdx.y;
  int k0 = ks * klen;
  int lane = t & 63, w = t >> 6;
  int wr = w >> 1, wc = w & 1;
  // A stage: chunk c = t -> LDS halfs [t*8, t*8+8)
  int rA = ((t >> 6) & 1)*32 + (t & 31);
  const _Float16* srcA = xh + (size_t)growL[rA]*FIN + k0
                       + (t >> 7)*16 + ((t >> 5) & 1)*8;
  // B stage: chunks c2 = q*256 + t -> LDS halfs 2048 + c2*8
  const _Float16* srcB[4];
  #pragma unroll
  for (int q = 0; q < 4; q++){
    int c2 = q*256 + t;
    int colg = ((c2 >> 6) & 7)*32 + (t & 31);
    srcB[q] = WhT + ((size_t)cam*FOUT + colg)*FIN + k0
            + (c2 >> 9)*16 + ((t >> 5) & 1)*8;
  }
  f32x16 acc[4];
  #pragma unroll
  for (int nb = 0; nb < 4; nb++)
    #pragma unroll
    for (int r = 0; r < 16; r++) acc[nb][r] = 0.f;

  int nsteps = klen >> 5;
  int cur = 0;
  // prologue: stage step 0
  gload16(srcA, &ab[0][t*8]);
  #pragma unroll
  for (int q = 0; q < 4; q++) gload16(srcB[q], &ab[0][2048 + (q*256 + t)*8]);
  __syncthreads();
  for (int s = 0; s < nsteps; s++){
    if (s + 1 < nsteps){
      int adv = (s + 1)*32;
      gload16(srcA + adv, &ab[cur ^ 1][t*8]);
      #pragma unroll
      for (int q = 0; q < 4; q++)
        gload16(srcB[q] + adv, &ab[cur ^ 1][2048 + (q*256 + t)*8]);
    }
    const _Float16* base = ab[cur];
    f16x8 af[2]; f16x8 bfr[2][4];
    #pragma unroll
    for (int kk = 0; kk < 2; kk++){
      af[kk] = *(const f16x8*)(base + ((kk*2 + wr)*64 + lane)*8);
      #pragma unroll
      for (int nb = 0; nb < 4; nb++)
        bfr[kk][nb] = *(const f16x8*)(base + 2048 + ((kk*8 + wc*4 + nb)*64 + lane)*8);
    }
    #pragma unroll
    for (int kk = 0; kk < 2; kk++)
      #pragma unroll
      for (int nb = 0; nb < 4; nb++)
        acc[nb] = __builtin_amdgcn_mfma_f32_32x32x16_f16(af[kk], bfr[kk][nb], acc[nb], 0, 0, 0);
    __syncthreads();   // drains vmcnt (staged DMA) + lgkm, then barrier
    cur ^= 1;
  }
  int colb = wc*128;
  #pragma unroll
  for (int nb = 0; nb < 4; nb++){
    #pragma unroll
    for (int r = 0; r < 16; r++){
      int rowl = wr*32 + (r & 3) + 8*(r >> 2) + 4*(lane >> 5);
      int grow = rows[rowl];
      if (grow >= 0)
        partial[((size_t)ks*NR + grow)*FOUT + colb + nb*32 + (lane & 31)] = acc[nb][r];
    }
  }
}

// ---------------- K4: reduce split-K partials -> h fp32 + h bf16 --------------
__global__ __launch_bounds__(256) void k_hsum(const float* __restrict__ partial,
    float* __restrict__ h, unsigned short* __restrict__ hbf, int ksplit){
  int g = blockIdx.x*256 + threadIdx.x;
  int row = g >> 6, c4 = (g & 63)*4;
  f32x4 s; s[0] = s[1] = s[2] = s[3] = 0.f;
  for (int ks = 0; ks < ksplit; ks++)
    s += *(const f32x4*)(partial + ((size_t)ks*NR + row)*FOUT + c4);
  u16x4 pk;
  #pragma unroll
  for (int e = 0; e < 4; e++) pk[e] = f2bf(s[e]);
  *(f32x4*)(h + (size_t)row*FOUT + c4) = s;
  *(u16x4*)(hbf + (size_t)row*FOUT + c4) = pk;
}

// ---------------- K5: s1 = h@a1, s2 = h@a2, per-block max(s2) -----------------
__global__ void k_svec(const float* __restrict__ h, const float* __restrict__ a,
                       float* __restrict__ s1, float* __restrict__ s2,
                       float* __restrict__ bm){
  __shared__ float a1l[FOUT], a2l[FOUT];
  __shared__ float red[128];
  int t = threadIdx.x;
  for (int k = t; k < FOUT; k += 128){ a1l[k] = a[k]; a2l[k] = a[FOUT + k]; }
  __syncthreads();
  int n = blockIdx.x*128 + t;
  const f32x4* h4 = (const f32x4*)(h + (size_t)n*FOUT);
  float acc1 = 0.f, acc2 = 0.f;
  #pragma unroll 4
  for (int q = 0; q < 64; q++){
    f32x4 hv = h4[q];
    f32x4 a1v = *(const f32x4*)&a1l[q*4];
    f32x4 a2v = *(const f32x4*)&a2l[q*4];
    #pragma unroll
    for (int e = 0; e < 4; e++){
      acc1 = fmaf(hv[e], a1v[e], acc1);
      acc2 = fmaf(hv[e], a2v[e], acc2);
    }
  }
  s1[n] = acc1; s2[n] = acc2;
  red[t] = acc2;
  __syncthreads();
  for (int s = 64; s > 0; s >>= 1){
    if (t < s) red[t] = fmaxf(red[t], red[t + s]);
    __syncthreads();
  }
  if (t == 0) bm[blockIdx.x] = red[0];
}

// ---------------- K6: transpose h_bf16 [NR][FOUT] -> hT [FOUT][NR] ------------
__global__ void k_transpose(const unsigned short* __restrict__ in,
                            unsigned short* __restrict__ out){
  __shared__ unsigned short tl[64][72];
  int t = threadIdx.x;
  int j0 = blockIdx.x*64, c0 = blockIdx.y*64;
  {
    int jj = t >> 2, cq = (t & 3)*16;
    union { u32x4 v[2]; unsigned short s[16]; } buf;
    const u32x4* src = (const u32x4*)(in + (size_t)(j0 + jj)*FOUT + c0 + cq);
    buf.v[0] = src[0]; buf.v[1] = src[1];
    #pragma unroll
    for (int k = 0; k < 16; k++) tl[cq + k][jj] = buf.s[k];
  }
  __syncthreads();
  {
    int cc = t >> 2, jq = (t & 3)*16;
    union { u32x4 v[2]; unsigned short s[16]; } buf;
    #pragma unroll
    for (int k = 0; k < 16; k++) buf.s[k] = tl[cc][jq + k];
    u32x4* dst = (u32x4*)(out + (size_t)(c0 + cc)*NR + j0 + jq);
    dst[0] = buf.v[0]; dst[1] = buf.v[1];
  }
}

// ---------------- K7: fused masked-softmax attention x h (flash-like) ---------
__global__ __launch_bounds__(512) void k_flash(const int* __restrict__ adj,
    const float* __restrict__ s1g, const float* __restrict__ s2g,
    const float* __restrict__ bm, const unsigned short* __restrict__ hT,
    float* __restrict__ hp, float* __restrict__ Dp, int jchunks){
  __shared__ unsigned short pl[64][72];
  __shared__ float s1l[64], ml[64], Dl[64], red[64];
  int t = threadIdx.x;
  int i0 = blockIdx.x*64;
  int jc = blockIdx.y;
  int nj = NR / jchunks;
  int jbase = jc * nj;
  if (t < 64) red[t] = bm[t];
  __syncthreads();
  if (t < 8){ float v = red[t]; for (int k = t + 8; k < 64; k += 8) v = fmaxf(v, red[k]); red[t] = v; }
  __syncthreads();
  if (t == 0){ float v = red[0]; for (int k = 1; k < 8; k++) v = fmaxf(v, red[k]); red[0] = v; }
  __syncthreads();
  float maxS2 = red[0];
  if (t < 64){
    float sv = s1g[i0 + t];
    s1l[t] = sv;
    float mm = sv + maxS2;
    ml[t] = fmaxf(mm, ALPHA*mm);
  }
  __syncthreads();
  int il = t >> 3, tj = t & 7;
  int w = t >> 6, lane = t & 63;
  float s1i = s1l[il], mi = ml[il];
  float Dacc = 0.f;
  f32x16 acc0, acc1;
  #pragma unroll
  for (int k = 0; k < 16; k++){ acc0[k] = 0.f; acc1[k] = 0.f; }
  const unsigned short* hTw = hT + (size_t)(w*32 + (lane & 31))*NR;
  const int* arow = adj + (size_t)(i0 + il)*NR + jbase + tj*8;
  for (int jt = 0; jt < nj; jt += 64){
    int j0 = jbase + jt;
    i32x4 ad0 = __builtin_nontemporal_load((const i32x4*)arow);
    i32x4 ad1 = __builtin_nontemporal_load(((const i32x4*)arow) + 1);
    arow += 64;
    f32x4 s20 = *(const f32x4*)(s2g + j0 + tj*8);
    f32x4 s21 = *(const f32x4*)(s2g + j0 + tj*8 + 4);
    u16x8 pu;
    float Dloc = 0.f;
    #pragma unroll
    for (int e = 0; e < 4; e++){
      float e0 = s1i + s20[e]; e0 = fmaxf(e0, ALPHA*e0);
      float p0 = (ad0[e] > 0) ? __expf(e0 - mi) : 0.f;
      unsigned short b0 = f2bf(p0); pu[e] = b0; Dloc += bf2f(b0);
      float e1 = s1i + s21[e]; e1 = fmaxf(e1, ALPHA*e1);
      float p1 = (ad1[e] > 0) ? __expf(e1 - mi) : 0.f;
      unsigned short b1 = f2bf(p1); pu[e + 4] = b1; Dloc += bf2f(b1);
    }
    Dacc += Dloc;
    bf16x8 bfr[4];
    #pragma unroll
    for (int ks = 0; ks < 4; ks++){
      int koff = ks*16 + (lane >> 5)*8;
      bfr[ks] = *(const bf16x8*)(hTw + j0 + koff);
    }
    *(u16x8*)&pl[il][tj*8] = pu;
    __syncthreads();
    #pragma unroll
    for (int ks = 0; ks < 4; ks++){
      int koff = ks*16 + (lane >> 5)*8;
      bf16x8 a0 = *(const bf16x8*)&pl[lane & 31][koff];
      acc0 = __builtin_amdgcn_mfma_f32_32x32x16_bf16(a0, bfr[ks], acc0, 0, 0, 0);
      bf16x8 a1 = *(const bf16x8*)&pl[32 + (lane & 31)][koff];
      acc1 = __builtin_amdgcn_mfma_f32_32x32x16_bf16(a1, bfr[ks], acc1, 0, 0, 0);
    }
    __syncthreads();
  }
  Dacc += __shfl_xor(Dacc, 1);
  Dacc += __shfl_xor(Dacc, 2);
  Dacc += __shfl_xor(Dacc, 4);
  if (tj == 0) Dl[il] = Dacc;
  __syncthreads();
  if (t < 64) Dp[(size_t)jc*NR + i0 + t] = Dl[t];
  float* hpb = hp + (size_t)jc*NR*FOUT;
  int col = w*32 + (lane & 31);
  #pragma unroll
  for (int r = 0; r < 16; r++){
    int rowl = (r & 3) + 8*(r >> 2) + 4*(lane >> 5);
    hpb[(size_t)(i0 + rowl)*FOUT + col] = acc0[r];
    hpb[(size_t)(i0 + 32 + rowl)*FOUT + col] = acc1[r];
  }
}

// ---------------- K8: combine partials, normalize, ELU ------------------------
__global__ void k_final(const float* __restrict__ hp, const float* __restrict__ Dp,
                        float* __restrict__ out, int jchunks){
  int g = blockIdx.x*256 + threadIdx.x;
  int i = g >> 6, cg = (g & 63)*4;
  f32x4 s; s[0] = s[1] = s[2] = s[3] = 0.f;
  float D = 0.f;
  for (int jc = 0; jc < jchunks; jc++){
    f32x4 v = *(const f32x4*)(hp + ((size_t)jc*NR + i)*FOUT + cg);
    s += v;
    D += Dp[(size_t)jc*NR + i];
  }
  float inv = (D > 0.f) ? 1.f / D : 0.f;
  f32x4 o;
  #pragma unroll
  for (int e = 0; e < 4; e++){
    float v = s[e]*inv;
    o[e] = (v > 0.f) ? v : expm1f(v);
  }
  *(f32x4*)(out + (size_t)i*FOUT + cg) = o;
}

extern "C" void kernel_launch(void* const* d_in, const int* in_sizes, int n_in,
                              void* d_out, int out_size, void* d_ws, size_t ws_size,
                              hipStream_t stream){
  (void)in_sizes; (void)n_in; (void)out_size;
  const float* x   = (const float*)d_in[0];
  const float* W   = (const float*)d_in[1];
  const float* a   = (const float*)d_in[2];
  const int*   cam = (const int*)d_in[3];
  const int*   adj = (const int*)d_in[4];
  float* out = (float*)d_out;
  char* ws = (char*)d_ws;

  // pick KSPLIT / JC so everything fits
  int KS = 4, JC = 4;
  for (;;){
    size_t need = 0;
    need += (size_t)NR*4 + 256;                    // rowlist
    need += (size_t)NTMAX*4 + 256;                 // tileCam
    need += (size_t)NTMAX*64*4 + 256;              // prows
    need += (size_t)NR*FIN*2 + 256;                // xh
    need += (size_t)8*FIN*FOUT*2 + 256;            // WhT
    need += (size_t)NR*FOUT*4 + 256;               // h
    need += (size_t)NR*FOUT*2 + 256;               // hbf
    need += (size_t)NR*FOUT*2 + 256;               // hT
    need += (size_t)NR*4*2 + 512;                  // s1, s2
    need += 512;                                   // bm
    need += (size_t)JC*NR*4 + 256;                 // Dp
    size_t sh1 = (size_t)KS*NR*FOUT*4;             // partial
    size_t sh2 = (size_t)JC*NR*FOUT*4;             // hp
    need += (sh1 > sh2 ? sh1 : sh2) + 256;         // shared region
    if (need <= ws_size || (KS == 1 && JC == 1)) break;
    if (KS > 1) KS >>= 1;
    if (JC > 1) JC >>= 1;
  }

  size_t off = 0;
  auto alloc = [&](size_t b) -> void* {
    void* p = ws + off; off = (off + b + 255) & ~(size_t)255; return p;
  };
  int* rowlist  = (int*)alloc((size_t)NR*4);
  int* tileCam  = (int*)alloc((size_t)NTMAX*4);
  int* prows    = (int*)alloc((size_t)NTMAX*64*4);
  _Float16* xh  = (_Float16*)alloc((size_t)NR*FIN*2);
  _Float16* WhT = (_Float16*)alloc((size_t)8*FIN*FOUT*2);
  float* h            = (float*)alloc((size_t)NR*FOUT*4);
  unsigned short* hbf = (unsigned short*)alloc((size_t)NR*FOUT*2);
  unsigned short* hT  = (unsigned short*)alloc((size_t)NR*FOUT*2);
  float* s1 = (float*)alloc((size_t)NR*4);
  float* s2 = (float*)alloc((size_t)NR*4);
  float* bm = (float*)alloc(64*4);
  float* Dp = (float*)alloc((size_t)JC*NR*4);
  size_t sh1 = (size_t)KS*NR*FOUT*4;
  size_t sh2 = (size_t)JC*NR*FOUT*4;
  void* shared = alloc(sh1 > sh2 ? sh1 : sh2);
  float* partial = (float*)shared;   // lifetime: k_gmm .. k_hsum
  float* hp      = (float*)shared;   // lifetime: k_flash .. k_final

  int klen = FIN / KS;

  hipLaunchKernelGGL(k_bucket, dim3(1), dim3(256), 0, stream,
                     cam, rowlist, tileCam, prows);
  hipLaunchKernelGGL(k_xhalf, dim3(NR*FIN/(256*32)), dim3(256), 0, stream, x, xh);
  hipLaunchKernelGGL(k_wth, dim3(FIN/64, FOUT/64, 8), dim3(256), 0, stream, W, WhT);
  hipLaunchKernelGGL(k_gmm, dim3(NTMAX, KS), dim3(256), 0, stream,
                     xh, WhT, tileCam, prows, partial, klen);
  hipLaunchKernelGGL(k_hsum, dim3(NR*64/256), dim3(256), 0, stream,
                     partial, h, hbf, KS);
  hipLaunchKernelGGL(k_svec, dim3(64), dim3(128), 0, stream, h, a, s1, s2, bm);
  hipLaunchKernelGGL(k_transpose, dim3(NR/64, FOUT/64), dim3(256), 0, stream, hbf, hT);
  hipLaunchKernelGGL(k_flash, dim3(NR/64, JC), dim3(512), 0, stream,
                     adj, s1, s2, bm, hT, hp, Dp, JC);
  hipLaunchKernelGGL(k_final, dim3((NR*FOUT/4)/256), dim3(256), 0, stream,
                     hp, Dp, out, JC);
}

// Round 3
// 236.327 us; speedup vs baseline: 2.1232x; 1.0918x over previous
//
#include <hip/hip_runtime.h>

#define NR 8192
#define FIN 2048
#define FOUT 256
#define ALPHA 0.2f
#define NTMAX 136

typedef float f32x4 __attribute__((ext_vector_type(4)));
typedef float f32x16 __attribute__((ext_vector_type(16)));
typedef int i32x4 __attribute__((ext_vector_type(4)));
typedef unsigned int u32x4 __attribute__((ext_vector_type(4)));
typedef unsigned short u16x4 __attribute__((ext_vector_type(4)));
typedef unsigned short u16x8 __attribute__((ext_vector_type(8)));
typedef __bf16 bf16x8 __attribute__((ext_vector_type(8)));
typedef _Float16 f16x8 __attribute__((ext_vector_type(8)));
typedef _Float16 f16x4 __attribute__((ext_vector_type(4)));

__device__ __forceinline__ unsigned short f2bf(float f){
  unsigned u = __float_as_uint(f);
  return (unsigned short)((u + 0x7fffu + ((u >> 16) & 1u)) >> 16);
}
__device__ __forceinline__ float bf2f(unsigned short b){
  return __uint_as_float(((unsigned)b) << 16);
}

__device__ __forceinline__ void gload16(const void* gptr, void* lptr){
  __builtin_amdgcn_global_load_lds(
      (const __attribute__((address_space(1))) unsigned int*)gptr,
      (__attribute__((address_space(3))) unsigned int*)lptr, 16, 0, 0);
}

// ---------------- K1: bucket rows by camera + tile table (1 block) -----------
__global__ void k_bucket(const int* __restrict__ cam, int* __restrict__ rowlist,
                         int* __restrict__ tileCam, int* __restrict__ prows){
  __shared__ int cnt[256][8];
  __shared__ int base[8];
  __shared__ int scnt[8];
  __shared__ int tstart[9];
  __shared__ int tcL[NTMAX], tlocL[NTMAX];
  int t = threadIdx.x;
  int loc[8];
  #pragma unroll
  for (int c = 0; c < 8; c++) loc[c] = 0;
  for (int k = 0; k < 32; k++){ int n = t*32 + k; loc[cam[n] & 7]++; }
  #pragma unroll
  for (int c = 0; c < 8; c++) cnt[t][c] = loc[c];
  __syncthreads();
  if (t < 8){
    int s = 0;
    for (int i = 0; i < 256; i++){ int v = cnt[i][t]; cnt[i][t] = s; s += v; }
    scnt[t] = s;
  }
  __syncthreads();
  if (t == 0){
    int s = 0;
    for (int c = 0; c < 8; c++){ base[c] = s; s += scnt[c]; }
    int ts = 0;
    for (int c = 0; c < 8; c++){ tstart[c] = ts; ts += (scnt[c] + 63) >> 6; }
    tstart[8] = ts;
  }
  __syncthreads();
  int off[8];
  #pragma unroll
  for (int c = 0; c < 8; c++) off[c] = base[c] + cnt[t][c];
  for (int k = 0; k < 32; k++){
    int n = t*32 + k; int c = cam[n] & 7;
    rowlist[off[c]++] = n;
  }
  __syncthreads();
  if (t < NTMAX){
    int tc = -1, tl = 0;
    if (t < tstart[8]){
      for (int c = 0; c < 8; c++)
        if (t >= tstart[c] && t < tstart[c+1]){ tc = c; tl = t - tstart[c]; }
    }
    tcL[t] = tc; tlocL[t] = tl;
    tileCam[t] = tc;
  }
  __syncthreads();
  for (int s = t; s < NTMAX*64; s += 256){
    int tile = s >> 6;
    int c = tcL[tile];
    int v = -1;
    if (c >= 0){
      int li = tlocL[tile]*64 + (s & 63);
      if (li < scnt[c]) v = rowlist[base[c] + li];
    }
    prows[s] = v;
  }
}

// ---------------- K2: W[c][k][n] fp32 -> WhT[c][n][k] fp16 --------------------
__global__ __launch_bounds__(256) void k_wth(const float* __restrict__ W,
                                             _Float16* __restrict__ WhT){
  __shared__ _Float16 tl[64][72];
  int t = threadIdx.x;
  int k0 = blockIdx.x*64, n0 = blockIdx.y*64, c = blockIdx.z;
  {
    int kk = t >> 2, nq = (t & 3)*16;
    const float* src = W + ((size_t)c*FIN + k0 + kk)*FOUT + n0 + nq;
    #pragma unroll
    for (int q = 0; q < 4; q++){
      f32x4 v = *(const f32x4*)(src + q*4);
      #pragma unroll
      for (int e = 0; e < 4; e++) tl[nq + q*4 + e][kk] = (_Float16)v[e];
    }
  }
  __syncthreads();
  {
    int nn = t >> 2, kq = (t & 3)*16;
    union { u32x4 v[2]; _Float16 s[16]; } buf;
    #pragma unroll
    for (int e = 0; e < 16; e++) buf.s[e] = tl[nn][kq + e];
    u32x4* dst = (u32x4*)(WhT + ((size_t)c*FOUT + n0 + nn)*FIN + k0 + kq);
    dst[0] = buf.v[0]; dst[1] = buf.v[1];
  }
}

// ---------------- K3: MFMA gather GEMM  partial[ks] = x[rows] @ W[c] ----------
// Block: 64 rows x 256 cols, 4 waves (2x2), BK=32 double-buffered, split-K.
// A reg-staged (fp32->fp16 cvt), B via per-lane-gather global_load_lds.
__global__ __launch_bounds__(256) void k_gmm(const float* __restrict__ x,
    const _Float16* __restrict__ WhT, const int* __restrict__ tileCam,
    const int* __restrict__ prows, float* __restrict__ partial, int klen){
  __shared__ _Float16 ab[2][10240];   // [A:2048 | B:8192] halfs per buffer
  __shared__ int rows[64];
  __shared__ int growL[64];
  int tile = blockIdx.x;
  int cam = tileCam[tile];
  if (cam < 0) return;
  int t = threadIdx.x;
  if (t < 64){ int r = prows[tile*64 + t]; rows[t] = r; growL[t] = (r < 0) ? 0 : r; }
  __syncthreads();
  int ks = blockIdx.y;
  int k0 = ks * klen;
  int lane = t & 63, w = t >> 6;
  int wr = w >> 1, wc = w & 1;
  // A stage: chunk t -> LDS halfs [t*8, t*8+8)
  int rA = ((t >> 6) & 1)*32 + (t & 31);
  int koffA = (t >> 7)*16 + ((t >> 5) & 1)*8;
  const float* srcA = x + (size_t)growL[rA]*FIN + k0 + koffA;
  // B stage: chunk c2 = q*256 + t -> LDS halfs 2048 + c2*8
  const _Float16* srcB[4];
  #pragma unroll
  for (int q = 0; q < 4; q++){
    int c2 = q*256 + t;
    int colg = ((c2 >> 6) & 7)*32 + (t & 31);
    srcB[q] = WhT + ((size_t)cam*FOUT + colg)*FIN + k0
            + (c2 >> 9)*16 + ((t >> 5) & 1)*8;
  }
  f32x16 acc[4];
  #pragma unroll
  for (int nb = 0; nb < 4; nb++)
    #pragma unroll
    for (int r = 0; r < 16; r++) acc[nb][r] = 0.f;

  int nsteps = klen >> 5;
  int cur = 0;
  // prologue: stage step 0
  {
    f32x4 a0 = *(const f32x4*)srcA;
    f32x4 a1 = *(const f32x4*)(srcA + 4);
    #pragma unroll
    for (int q = 0; q < 4; q++) gload16(srcB[q], &ab[0][2048 + (q*256 + t)*8]);
    f16x8 hv;
    #pragma unroll
    for (int e = 0; e < 4; e++){ hv[e] = (_Float16)a0[e]; hv[4+e] = (_Float16)a1[e]; }
    *(f16x8*)&ab[0][t*8] = hv;
  }
  __syncthreads();
  for (int s = 0; s < nsteps; s++){
    bool have = (s + 1 < nsteps);
    int adv = have ? (s + 1)*32 : 0;
    // issue next A (regs) early; issue next B DMA
    f32x4 na0 = *(const f32x4*)(srcA + adv);
    f32x4 na1 = *(const f32x4*)(srcA + adv + 4);
    if (have){
      #pragma unroll
      for (int q = 0; q < 4; q++)
        gload16(srcB[q] + adv, &ab[cur ^ 1][2048 + (q*256 + t)*8]);
    }
    const _Float16* base = ab[cur];
    f16x8 af[2]; f16x8 bfr[2][4];
    #pragma unroll
    for (int kk = 0; kk < 2; kk++){
      af[kk] = *(const f16x8*)(base + ((kk*2 + wr)*64 + lane)*8);
      #pragma unroll
      for (int nb = 0; nb < 4; nb++)
        bfr[kk][nb] = *(const f16x8*)(base + 2048 + ((kk*8 + wc*4 + nb)*64 + lane)*8);
    }
    #pragma unroll
    for (int kk = 0; kk < 2; kk++)
      #pragma unroll
      for (int nb = 0; nb < 4; nb++)
        acc[nb] = __builtin_amdgcn_mfma_f32_32x32x16_f16(af[kk], bfr[kk][nb], acc[nb], 0, 0, 0);
    if (have){
      f16x8 hv;
      #pragma unroll
      for (int e = 0; e < 4; e++){ hv[e] = (_Float16)na0[e]; hv[4+e] = (_Float16)na1[e]; }
      *(f16x8*)&ab[cur ^ 1][t*8] = hv;
    }
    __syncthreads();
    cur ^= 1;
  }
  int colb = wc*128;
  #pragma unroll
  for (int nb = 0; nb < 4; nb++){
    #pragma unroll
    for (int r = 0; r < 16; r++){
      int rowl = wr*32 + (r & 3) + 8*(r >> 2) + 4*(lane >> 5);
      int grow = rows[rowl];
      if (grow >= 0)
        partial[((size_t)ks*NR + grow)*FOUT + colb + nb*32 + (lane & 31)] = acc[nb][r];
    }
  }
}

// ---------------- K4: reduce split-K -> hbf + s1/s2 + per-block max(s2) -------
__global__ __launch_bounds__(256) void k_hsum(const float* __restrict__ partial,
    const float* __restrict__ a, unsigned short* __restrict__ hbf,
    float* __restrict__ s1, float* __restrict__ s2, float* __restrict__ bm,
    int ksplit){
  __shared__ float a1l[FOUT], a2l[FOUT];
  __shared__ float smax[4];
  int t = threadIdx.x;
  a1l[t] = a[t]; a2l[t] = a[FOUT + t];
  __syncthreads();
  int w = t >> 6, lane = t & 63;
  int row = blockIdx.x*4 + w;
  f32x4 s; s[0] = s[1] = s[2] = s[3] = 0.f;
  for (int ks = 0; ks < ksplit; ks++)
    s += *(const f32x4*)(partial + ((size_t)ks*NR + row)*FOUT + lane*4);
  u16x4 pk;
  #pragma unroll
  for (int e = 0; e < 4; e++) pk[e] = f2bf(s[e]);
  *(u16x4*)(hbf + (size_t)row*FOUT + lane*4) = pk;
  f32x4 a1v = *(const f32x4*)&a1l[lane*4];
  f32x4 a2v = *(const f32x4*)&a2l[lane*4];
  float p1 = 0.f, p2 = 0.f;
  #pragma unroll
  for (int e = 0; e < 4; e++){ p1 = fmaf(s[e], a1v[e], p1); p2 = fmaf(s[e], a2v[e], p2); }
  #pragma unroll
  for (int off = 32; off > 0; off >>= 1){
    p1 += __shfl_xor(p1, off);
    p2 += __shfl_xor(p2, off);
  }
  if (lane == 0){ s1[row] = p1; s2[row] = p2; smax[w] = p2; }
  __syncthreads();
  if (t == 0)
    bm[blockIdx.x] = fmaxf(fmaxf(smax[0], smax[1]), fmaxf(smax[2], smax[3]));
}

// ---------------- K5: transpose h_bf16 [NR][FOUT] -> hT [FOUT][NR] ------------
__global__ void k_transpose(const unsigned short* __restrict__ in,
                            unsigned short* __restrict__ out){
  __shared__ unsigned short tl[64][72];
  int t = threadIdx.x;
  int j0 = blockIdx.x*64, c0 = blockIdx.y*64;
  {
    int jj = t >> 2, cq = (t & 3)*16;
    union { u32x4 v[2]; unsigned short s[16]; } buf;
    const u32x4* src = (const u32x4*)(in + (size_t)(j0 + jj)*FOUT + c0 + cq);
    buf.v[0] = src[0]; buf.v[1] = src[1];
    #pragma unroll
    for (int k = 0; k < 16; k++) tl[cq + k][jj] = buf.s[k];
  }
  __syncthreads();
  {
    int cc = t >> 2, jq = (t & 3)*16;
    union { u32x4 v[2]; unsigned short s[16]; } buf;
    #pragma unroll
    for (int k = 0; k < 16; k++) buf.s[k] = tl[cc][jq + k];
    u32x4* dst = (u32x4*)(out + (size_t)(c0 + cc)*NR + j0 + jq);
    dst[0] = buf.v[0]; dst[1] = buf.v[1];
  }
}

// ---------------- K6: fused masked-softmax attention x h (flash-like) ---------
__global__ __launch_bounds__(512) void k_flash(const int* __restrict__ adj,
    const float* __restrict__ s1g, const float* __restrict__ s2g,
    const float* __restrict__ bm, const unsigned short* __restrict__ hT,
    float* __restrict__ hp, float* __restrict__ Dp, int jchunks){
  __shared__ unsigned short pl[64][72];
  __shared__ float s1l[64], ml[64], Dl[64], red[8];
  int t = threadIdx.x;
  int i0 = blockIdx.x*64;
  int jc = blockIdx.y;
  int nj = NR / jchunks;
  int jbase = jc * nj;
  int w = t >> 6, lane = t & 63;
  // global max of s2 over 2048 per-block maxima
  {
    float v = -3.0e38f;
    for (int k = t; k < NR/4; k += 512) v = fmaxf(v, bm[k]);
    #pragma unroll
    for (int off = 32; off > 0; off >>= 1) v = fmaxf(v, __shfl_xor(v, off));
    if (lane == 0) red[w] = v;
  }
  __syncthreads();
  if (t == 0){
    float v = red[0];
    #pragma unroll
    for (int k = 1; k < 8; k++) v = fmaxf(v, red[k]);
    red[0] = v;
  }
  __syncthreads();
  float maxS2 = red[0];
  if (t < 64){
    float sv = s1g[i0 + t];
    s1l[t] = sv;
    float mm = sv + maxS2;
    ml[t] = fmaxf(mm, ALPHA*mm);
  }
  __syncthreads();
  int il = t >> 3, tj = t & 7;
  float s1i = s1l[il], mi = ml[il];
  float Dacc = 0.f;
  f32x16 acc0, acc1;
  #pragma unroll
  for (int k = 0; k < 16; k++){ acc0[k] = 0.f; acc1[k] = 0.f; }
  const unsigned short* hTw = hT + (size_t)(w*32 + (lane & 31))*NR;
  const int* arow = adj + (size_t)(i0 + il)*NR + jbase + tj*8;
  // prefetch tile 0
  i32x4 ad0 = __builtin_nontemporal_load((const i32x4*)arow);
  i32x4 ad1 = __builtin_nontemporal_load(((const i32x4*)arow) + 1);
  f32x4 s20 = *(const f32x4*)(s2g + jbase + tj*8);
  f32x4 s21 = *(const f32x4*)(s2g + jbase + tj*8 + 4);
  for (int jt = 0; jt < nj; jt += 64){
    int j0 = jbase + jt;
    i32x4 c0 = ad0, c1 = ad1;
    f32x4 t0 = s20, t1 = s21;
    if (jt + 64 < nj){
      arow += 64;
      ad0 = __builtin_nontemporal_load((const i32x4*)arow);
      ad1 = __builtin_nontemporal_load(((const i32x4*)arow) + 1);
      s20 = *(const f32x4*)(s2g + j0 + 64 + tj*8);
      s21 = *(const f32x4*)(s2g + j0 + 64 + tj*8 + 4);
    }
    u16x8 pu;
    float Dloc = 0.f;
    #pragma unroll
    for (int e = 0; e < 4; e++){
      float e0 = s1i + t0[e]; e0 = fmaxf(e0, ALPHA*e0);
      float p0 = (c0[e] > 0) ? __expf(e0 - mi) : 0.f;
      unsigned short b0 = f2bf(p0); pu[e] = b0; Dloc += bf2f(b0);
      float e1 = s1i + t1[e]; e1 = fmaxf(e1, ALPHA*e1);
      float p1 = (c1[e] > 0) ? __expf(e1 - mi) : 0.f;
      unsigned short b1 = f2bf(p1); pu[e + 4] = b1; Dloc += bf2f(b1);
    }
    Dacc += Dloc;
    bf16x8 bfr[4];
    #pragma unroll
    for (int ks = 0; ks < 4; ks++){
      int koff = ks*16 + (lane >> 5)*8;
      bfr[ks] = *(const bf16x8*)(hTw + j0 + koff);
    }
    *(u16x8*)&pl[il][tj*8] = pu;
    __syncthreads();
    #pragma unroll
    for (int ks = 0; ks < 4; ks++){
      int koff = ks*16 + (lane >> 5)*8;
      bf16x8 a0 = *(const bf16x8*)&pl[lane & 31][koff];
      acc0 = __builtin_amdgcn_mfma_f32_32x32x16_bf16(a0, bfr[ks], acc0, 0, 0, 0);
      bf16x8 a1 = *(const bf16x8*)&pl[32 + (lane & 31)][koff];
      acc1 = __builtin_amdgcn_mfma_f32_32x32x16_bf16(a1, bfr[ks], acc1, 0, 0, 0);
    }
    __syncthreads();
  }
  Dacc += __shfl_xor(Dacc, 1);
  Dacc += __shfl_xor(Dacc, 2);
  Dacc += __shfl_xor(Dacc, 4);
  if (tj == 0) Dl[il] = Dacc;
  __syncthreads();
  if (t < 64) Dp[(size_t)jc*NR + i0 + t] = Dl[t];
  float* hpb = hp + (size_t)jc*NR*FOUT;
  int col = w*32 + (lane & 31);
  #pragma unroll
  for (int r = 0; r < 16; r++){
    int rowl = (r & 3) + 8*(r >> 2) + 4*(lane >> 5);
    hpb[(size_t)(i0 + rowl)*FOUT + col] = acc0[r];
    hpb[(size_t)(i0 + 32 + rowl)*FOUT + col] = acc1[r];
  }
}

// ---------------- K7: combine partials, normalize, ELU ------------------------
__global__ void k_final(const float* __restrict__ hp, const float* __restrict__ Dp,
                        float* __restrict__ out, int jchunks){
  int g = blockIdx.x*256 + threadIdx.x;
  int i = g >> 6, cg = (g & 63)*4;
  f32x4 s; s[0] = s[1] = s[2] = s[3] = 0.f;
  float D = 0.f;
  for (int jc = 0; jc < jchunks; jc++){
    f32x4 v = *(const f32x4*)(hp + ((size_t)jc*NR + i)*FOUT + cg);
    s += v;
    D += Dp[(size_t)jc*NR + i];
  }
  float inv = (D > 0.f) ? 1.f / D : 0.f;
  f32x4 o;
  #pragma unroll
  for (int e = 0; e < 4; e++){
    float v = s[e]*inv;
    o[e] = (v > 0.f) ? v : expm1f(v);
  }
  *(f32x4*)(out + (size_t)i*FOUT + cg) = o;
}

extern "C" void kernel_launch(void* const* d_in, const int* in_sizes, int n_in,
                              void* d_out, int out_size, void* d_ws, size_t ws_size,
                              hipStream_t stream){
  (void)in_sizes; (void)n_in; (void)out_size;
  const float* x   = (const float*)d_in[0];
  const float* W   = (const float*)d_in[1];
  const float* a   = (const float*)d_in[2];
  const int*   cam = (const int*)d_in[3];
  const int*   adj = (const int*)d_in[4];
  float* out = (float*)d_out;
  char* ws = (char*)d_ws;

  int KS = 4, JC = 4;
  for (;;){
    size_t need = 0;
    need += (size_t)NR*4 + 256;                    // rowlist
    need += (size_t)NTMAX*4 + 256;                 // tileCam
    need += (size_t)NTMAX*64*4 + 256;              // prows
    need += (size_t)8*FIN*FOUT*2 + 256;            // WhT
    need += (size_t)NR*FOUT*2 + 256;               // hbf
    need += (size_t)NR*FOUT*2 + 256;               // hT
    need += (size_t)NR*4*2 + 512;                  // s1, s2
    need += (size_t)(NR/4)*4 + 256;                // bm
    need += (size_t)JC*NR*4 + 256;                 // Dp
    size_t sh1 = (size_t)KS*NR*FOUT*4;             // partial
    size_t sh2 = (size_t)JC*NR*FOUT*4;             // hp
    need += (sh1 > sh2 ? sh1 : sh2) + 256;         // shared region
    if (need <= ws_size || (KS == 1 && JC == 1)) break;
    if (KS > 1) KS >>= 1;
    if (JC > 1) JC >>= 1;
  }

  size_t off = 0;
  auto alloc = [&](size_t b) -> void* {
    void* p = ws + off; off = (off + b + 255) & ~(size_t)255; return p;
  };
  int* rowlist  = (int*)alloc((size_t)NR*4);
  int* tileCam  = (int*)alloc((size_t)NTMAX*4);
  int* prows    = (int*)alloc((size_t)NTMAX*64*4);
  _Float16* WhT = (_Float16*)alloc((size_t)8*FIN*FOUT*2);
  unsigned short* hbf = (unsigned short*)alloc((size_t)NR*FOUT*2);
  unsigned short* hT  = (unsigned short*)alloc((size_t)NR*FOUT*2);
  float* s1 = (float*)alloc((size_t)NR*4);
  float* s2 = (float*)alloc((size_t)NR*4);
  float* bm = (float*)alloc((size_t)(NR/4)*4);
  float* Dp = (float*)alloc((size_t)JC*NR*4);
  size_t sh1 = (size_t)KS*NR*FOUT*4;
  size_t sh2 = (size_t)JC*NR*FOUT*4;
  void* shared = alloc(sh1 > sh2 ? sh1 : sh2);
  float* partial = (float*)shared;   // lifetime: k_gmm .. k_hsum
  float* hp      = (float*)shared;   // lifetime: k_flash .. k_final

  int klen = FIN / KS;

  hipLaunchKernelGGL(k_bucket, dim3(1), dim3(256), 0, stream,
                     cam, rowlist, tileCam, prows);
  hipLaunchKernelGGL(k_wth, dim3(FIN/64, FOUT/64, 8), dim3(256), 0, stream, W, WhT);
  hipLaunchKernelGGL(k_gmm, dim3(NTMAX, KS), dim3(256), 0, stream,
                     x, WhT, tileCam, prows, partial, klen);
  hipLaunchKernelGGL(k_hsum, dim3(NR/4), dim3(256), 0, stream,
                     partial, a, hbf, s1, s2, bm, KS);
  hipLaunchKernelGGL(k_transpose, dim3(NR/64, FOUT/64), dim3(256), 0, stream, hbf, hT);
  hipLaunchKernelGGL(k_flash, dim3(NR/64, JC), dim3(512), 0, stream,
                     adj, s1, s2, bm, hT, hp, Dp, JC);
  hipLaunchKernelGGL(k_final, dim3((NR*FOUT/4)/256), dim3(256), 0, stream,
                     hp, Dp, out, JC);
}